// Round 1
// baseline (428.224 us; speedup 1.0000x reference)
//
#include <hip/hip_runtime.h>
#include <hip/hip_bf16.h>

#define T_TOK 2048
#define DIM   1024
#define FF    2048
#define NE    8

typedef _Float16 f16x8 __attribute__((ext_vector_type(8)));
typedef _Float16 f16x4 __attribute__((ext_vector_type(4)));
typedef float    f32x4 __attribute__((ext_vector_type(4)));

// ---------------- router: logits, softmax, top1/top2, gates ----------------
__global__ __launch_bounds__(256) void router_kernel(
    const float* __restrict__ x,        // [T, D]
    const float* __restrict__ rw,       // [D, E]
    float* __restrict__ gates_out,      // [T, E]
    float* __restrict__ top1_out,       // [T]
    int*   __restrict__ meta,           // [0..7]=counts
    int* __restrict__ e1a, int* __restrict__ e2a,
    float* __restrict__ g1a, float* __restrict__ g2a)
{
    const int wid  = threadIdx.x >> 6;
    const int lane = threadIdx.x & 63;
    const int t = blockIdx.x * 4 + wid;

    float acc[NE];
#pragma unroll
    for (int e = 0; e < NE; ++e) acc[e] = 0.f;

#pragma unroll
    for (int i = 0; i < 4; ++i) {
        const int d0 = i * 256 + lane * 4;
        f32x4 xv = *(const f32x4*)&x[(size_t)t * DIM + d0];
#pragma unroll
        for (int j = 0; j < 4; ++j) {
            f32x4 wa = *(const f32x4*)&rw[(size_t)(d0 + j) * NE];
            f32x4 wb = *(const f32x4*)&rw[(size_t)(d0 + j) * NE + 4];
            float xs = xv[j];
            acc[0] += xs * wa[0]; acc[1] += xs * wa[1];
            acc[2] += xs * wa[2]; acc[3] += xs * wa[3];
            acc[4] += xs * wb[0]; acc[5] += xs * wb[1];
            acc[6] += xs * wb[2]; acc[7] += xs * wb[3];
        }
    }
#pragma unroll
    for (int off = 32; off > 0; off >>= 1) {
#pragma unroll
        for (int e = 0; e < NE; ++e)
            acc[e] += __shfl_xor(acc[e], off, 64);
    }

    // softmax (fp32)
    float mx = acc[0];
#pragma unroll
    for (int e = 1; e < NE; ++e) mx = fmaxf(mx, acc[e]);
    float pr[NE]; float s = 0.f;
#pragma unroll
    for (int e = 0; e < NE; ++e) { pr[e] = expf(acc[e] - mx); s += pr[e]; }

    // top1 = first argmax of logits (== argmax probs)
    int e1 = 0; float b1v = acc[0];
#pragma unroll
    for (int e = 1; e < NE; ++e) if (acc[e] > b1v) { b1v = acc[e]; e1 = e; }
    // top2 = argmax of logits with top1 masked
    int e2 = (e1 == 0) ? 1 : 0; float b2v = acc[e2];
#pragma unroll
    for (int e = 0; e < NE; ++e)
        if (e != e1 && acc[e] > b2v) { b2v = acc[e]; e2 = e; }

    float p1 = pr[e1] / s, p2 = pr[e2] / s;
    float denom = fmaxf(p1 + p2, 1.1920929e-07f);
    float gg1 = p1 / denom, gg2 = p2 / denom;

    if (lane == 0) {
#pragma unroll
        for (int e = 0; e < NE; ++e)
            gates_out[(size_t)t * NE + e] = (e == e1) ? gg1 : ((e == e2) ? gg2 : 0.f);
        top1_out[t] = (float)e1;
        e1a[t] = e1; e2a[t] = e2; g1a[t] = gg1; g2a[t] = gg2;
        atomicAdd(&meta[e1], 1);
        atomicAdd(&meta[e2], 1);
    }
}

// ---------------- scan: exclusive prefix over 8 counts ----------------
__global__ void scan_kernel(int* __restrict__ meta) {
    if (threadIdx.x == 0) {
        int s = 0;
#pragma unroll
        for (int e = 0; e < NE; ++e) { meta[8 + e] = s; s += meta[e]; }
    }
}

// ---------------- compaction: build per-expert token lists ----------------
__global__ void compact_kernel(const int* __restrict__ e1a, const int* __restrict__ e2a,
                               int* __restrict__ meta, int* __restrict__ atok,
                               int* __restrict__ tslot)
{
    int t = blockIdx.x * blockDim.x + threadIdx.x;
    if (t >= T_TOK) return;
    int e1 = e1a[t], e2 = e2a[t];
    int s1 = meta[8 + e1] + atomicAdd(&meta[16 + e1], 1);
    atok[s1] = t; tslot[2 * t] = s1;
    int s2 = meta[8 + e2] + atomicAdd(&meta[16 + e2], 1);
    atok[s2] = t; tslot[2 * t + 1] = s2;
}

static __device__ __forceinline__ _Float16 f2h(float f) { return (_Float16)f; }

// ---------------- fc1: H = relu(Xg @ W1[e] + b1[e]), fp16 MFMA ----------------
__global__ __launch_bounds__(256) void fc1_kernel(
    const float* __restrict__ x,        // [T, D]
    const float* __restrict__ w1,       // [E, D, F]
    const float* __restrict__ b1,       // [E, F]
    const int* __restrict__ meta,
    const int* __restrict__ atok,
    _Float16* __restrict__ H)           // [2T, F]
{
    const int e   = blockIdx.z;
    const int cnt = meta[e];
    const int m0  = blockIdx.y * 128;
    if (m0 >= cnt) return;
    const int base = meta[8 + e];
    const int n0   = blockIdx.x * 128;

    __shared__ _Float16 As[128][40];
    __shared__ _Float16 Bs[128][40];

    const int tid  = threadIdx.x;
    const int wid  = tid >> 6;
    const int lane = tid & 63;
    const int wr = wid >> 1, wc = wid & 1;

    // A staging map: 8 float4 per 32-wide row
    const int kv = tid & 7;        // which float4 in row
    const int r0 = tid >> 3;       // 0..31
    int tokr[4];
#pragma unroll
    for (int p = 0; p < 4; ++p) {
        int rg = m0 + r0 + p * 32;
        tokr[p] = (rg < cnt) ? atok[base + rg] : -1;
    }

    // B staging map: thread owns one n-column, half of k
    const int bn  = tid & 127;
    const int bkh = (tid >> 7) * 16;
    const float* Bp = w1 + (size_t)e * DIM * FF + n0 + bn;

    f32x4 acc[4][4];
#pragma unroll
    for (int mi = 0; mi < 4; ++mi)
#pragma unroll
        for (int ni = 0; ni < 4; ++ni) acc[mi][ni] = (f32x4)0.0f;

    for (int k0 = 0; k0 < DIM; k0 += 32) {
        // stage A (gather rows, convert fp32->fp16)
#pragma unroll
        for (int p = 0; p < 4; ++p) {
            int r = r0 + p * 32;
            f32x4 v = (f32x4)0.0f;
            if (tokr[p] >= 0)
                v = *(const f32x4*)&x[(size_t)tokr[p] * DIM + k0 + kv * 4];
            f16x4 hv; hv[0] = f2h(v[0]); hv[1] = f2h(v[1]); hv[2] = f2h(v[2]); hv[3] = f2h(v[3]);
            *(f16x4*)&As[r][kv * 4] = hv;
        }
        // stage B transposed: Bs[n][k]
        float bv[16];
#pragma unroll
        for (int i = 0; i < 16; ++i)
            bv[i] = Bp[(size_t)(k0 + bkh + i) * FF];
#pragma unroll
        for (int i4 = 0; i4 < 4; ++i4) {
            f16x4 hv; hv[0] = f2h(bv[i4*4]); hv[1] = f2h(bv[i4*4+1]);
            hv[2] = f2h(bv[i4*4+2]); hv[3] = f2h(bv[i4*4+3]);
            *(f16x4*)&Bs[bn][bkh + i4 * 4] = hv;
        }
        __syncthreads();

        const int ksub = (lane >> 4) * 8;
        f16x8 af[4], bf[4];
#pragma unroll
        for (int mi = 0; mi < 4; ++mi)
            af[mi] = *(const f16x8*)&As[wr * 64 + mi * 16 + (lane & 15)][ksub];
#pragma unroll
        for (int ni = 0; ni < 4; ++ni)
            bf[ni] = *(const f16x8*)&Bs[wc * 64 + ni * 16 + (lane & 15)][ksub];
#pragma unroll
        for (int mi = 0; mi < 4; ++mi)
#pragma unroll
            for (int ni = 0; ni < 4; ++ni)
                acc[mi][ni] = __builtin_amdgcn_mfma_f32_16x16x32_f16(af[mi], bf[ni], acc[mi][ni], 0, 0, 0);
        __syncthreads();
    }

    const int crow = wr * 64 + ((lane >> 4) * 4);
    const int ccol = wc * 64 + (lane & 15);
#pragma unroll
    for (int ni = 0; ni < 4; ++ni) {
        int n = n0 + ccol + ni * 16;
        float bias = b1[(size_t)e * FF + n];
#pragma unroll
        for (int mi = 0; mi < 4; ++mi) {
#pragma unroll
            for (int r = 0; r < 4; ++r) {
                int rg = m0 + crow + mi * 16 + r;
                if (rg < cnt) {
                    float v = fmaxf(acc[mi][ni][r] + bias, 0.f);
                    H[(size_t)(base + rg) * FF + n] = f2h(v);
                }
            }
        }
    }
}

// ---------------- fc2: Y = H @ W2[e] + b2[e] ----------------
__global__ __launch_bounds__(256) void fc2_kernel(
    const _Float16* __restrict__ H,     // [2T, F]
    const float* __restrict__ w2,       // [E, F, D]
    const float* __restrict__ b2,       // [E, D]
    const int* __restrict__ meta,
    float* __restrict__ Y)              // [2T, D]
{
    const int e   = blockIdx.z;
    const int cnt = meta[e];
    const int m0  = blockIdx.y * 128;
    if (m0 >= cnt) return;
    const int base = meta[8 + e];
    const int n0   = blockIdx.x * 128;

    __shared__ _Float16 As[128][40];
    __shared__ _Float16 Bs[128][40];

    const int tid  = threadIdx.x;
    const int wid  = tid >> 6;
    const int lane = tid & 63;
    const int wr = wid >> 1, wc = wid & 1;

    // A staging: 4 x f16x8 chunks per 32-wide row
    const int kv2 = tid & 3;       // which f16x8 chunk
    const int r0  = tid >> 2;      // 0..63
    // B staging
    const int bn  = tid & 127;
    const int bkh = (tid >> 7) * 16;
    const float* Bp = w2 + (size_t)e * FF * DIM + n0 + bn;

    f32x4 acc[4][4];
#pragma unroll
    for (int mi = 0; mi < 4; ++mi)
#pragma unroll
        for (int ni = 0; ni < 4; ++ni) acc[mi][ni] = (f32x4)0.0f;

    for (int k0 = 0; k0 < FF; k0 += 32) {
#pragma unroll
        for (int p = 0; p < 2; ++p) {
            int r = r0 + p * 64;
            int slot = base + m0 + r;
            slot = (slot < 2 * T_TOK) ? slot : (2 * T_TOK - 1);
            f16x8 v = *(const f16x8*)&H[(size_t)slot * FF + k0 + kv2 * 8];
            *(f16x8*)&As[r][kv2 * 8] = v;
        }
        float bv[16];
#pragma unroll
        for (int i = 0; i < 16; ++i)
            bv[i] = Bp[(size_t)(k0 + bkh + i) * DIM];
#pragma unroll
        for (int i4 = 0; i4 < 4; ++i4) {
            f16x4 hv; hv[0] = f2h(bv[i4*4]); hv[1] = f2h(bv[i4*4+1]);
            hv[2] = f2h(bv[i4*4+2]); hv[3] = f2h(bv[i4*4+3]);
            *(f16x4*)&Bs[bn][bkh + i4 * 4] = hv;
        }
        __syncthreads();

        const int ksub = (lane >> 4) * 8;
        f16x8 af[4], bf[4];
#pragma unroll
        for (int mi = 0; mi < 4; ++mi)
            af[mi] = *(const f16x8*)&As[wr * 64 + mi * 16 + (lane & 15)][ksub];
#pragma unroll
        for (int ni = 0; ni < 4; ++ni)
            bf[ni] = *(const f16x8*)&Bs[wc * 64 + ni * 16 + (lane & 15)][ksub];
#pragma unroll
        for (int mi = 0; mi < 4; ++mi)
#pragma unroll
            for (int ni = 0; ni < 4; ++ni)
                acc[mi][ni] = __builtin_amdgcn_mfma_f32_16x16x32_f16(af[mi], bf[ni], acc[mi][ni], 0, 0, 0);
        __syncthreads();
    }

    const int crow = wr * 64 + ((lane >> 4) * 4);
    const int ccol = wc * 64 + (lane & 15);
#pragma unroll
    for (int ni = 0; ni < 4; ++ni) {
        int n = n0 + ccol + ni * 16;
        float bias = b2[(size_t)e * DIM + n];
#pragma unroll
        for (int mi = 0; mi < 4; ++mi) {
#pragma unroll
            for (int r = 0; r < 4; ++r) {
                int rg = m0 + crow + mi * 16 + r;
                if (rg < cnt)
                    Y[(size_t)(base + rg) * DIM + n] = acc[mi][ni][r] + bias;
            }
        }
    }
}

// ---------------- combine: out = g1*y1 + g2*y2, where(==0, x) ----------------
__global__ __launch_bounds__(256) void combine_kernel(
    const float* __restrict__ x, const float* __restrict__ Y,
    const int* __restrict__ tslot, const float* __restrict__ g1a,
    const float* __restrict__ g2a, float* __restrict__ out)
{
    const int t = blockIdx.x;
    const int d = threadIdx.x * 4;
    const int s1 = tslot[2 * t], s2 = tslot[2 * t + 1];
    const float a = g1a[t], b = g2a[t];
    f32x4 y1 = *(const f32x4*)&Y[(size_t)s1 * DIM + d];
    f32x4 y2 = *(const f32x4*)&Y[(size_t)s2 * DIM + d];
    f32x4 xv = *(const f32x4*)&x[(size_t)t * DIM + d];
    f32x4 o;
#pragma unroll
    for (int j = 0; j < 4; ++j) {
        float v = a * y1[j] + b * y2[j];
        o[j] = (v == 0.f) ? xv[j] : v;
    }
    *(f32x4*)&out[(size_t)t * DIM + d] = o;
}

extern "C" void kernel_launch(void* const* d_in, const int* in_sizes, int n_in,
                              void* d_out, int out_size, void* d_ws, size_t ws_size,
                              hipStream_t stream) {
    (void)in_sizes; (void)n_in; (void)out_size; (void)ws_size;
    const float* x  = (const float*)d_in[0];
    const float* rw = (const float*)d_in[1];
    const float* w1 = (const float*)d_in[2];
    const float* b1 = (const float*)d_in[3];
    const float* w2 = (const float*)d_in[4];
    const float* b2 = (const float*)d_in[5];

    float* out       = (float*)d_out;
    float* gates_out = out + (size_t)T_TOK * DIM;
    float* top1_out  = gates_out + (size_t)T_TOK * NE;

    char* ws = (char*)d_ws;
    int*   meta  = (int*)ws;                       // [0..7] counts, [8..15] base, [16..23] cursor
    int*   e1a   = (int*)(ws + 1024);
    int*   e2a   = (int*)(ws + 1024 + 8192);
    float* g1a   = (float*)(ws + 1024 + 2 * 8192);
    float* g2a   = (float*)(ws + 1024 + 3 * 8192);
    int*   atok  = (int*)(ws + 1024 + 4 * 8192);   // [2T]
    int*   tslot = (int*)(ws + 1024 + 4 * 8192 + 16384); // [2T]
    _Float16* H  = (_Float16*)(ws + 66560);        // [2T, F] fp16
    float*    Y  = (float*)(ws + 66560 + (size_t)2 * T_TOK * FF * 2); // [2T, D] f32

    hipMemsetAsync(meta, 0, 256, stream);
    router_kernel<<<T_TOK / 4, 256, 0, stream>>>(x, rw, gates_out, top1_out, meta, e1a, e2a, g1a, g2a);
    scan_kernel<<<1, 64, 0, stream>>>(meta);
    compact_kernel<<<T_TOK / 256, 256, 0, stream>>>(e1a, e2a, meta, atok, tslot);
    fc1_kernel<<<dim3(FF / 128, 16, NE), 256, 0, stream>>>(x, w1, b1, meta, atok, H);
    fc2_kernel<<<dim3(DIM / 128, 16, NE), 256, 0, stream>>>(H, w2, b2, meta, Y);
    combine_kernel<<<T_TOK, 256, 0, stream>>>(x, Y, tslot, g1a, g2a, out);
}

// Round 4
// 332.483 us; speedup vs baseline: 1.2880x; 1.2880x over previous
//
#include <hip/hip_runtime.h>

#define T_TOK 2048
#define DIM   1024
#define FF    2048
#define NE    8
#define MAXTILES 40

typedef _Float16 f16x2 __attribute__((ext_vector_type(2)));
typedef _Float16 f16x4 __attribute__((ext_vector_type(4)));
typedef _Float16 f16x8 __attribute__((ext_vector_type(8)));
typedef float    f32x4 __attribute__((ext_vector_type(4)));

__device__ __forceinline__ f16x2 cvtpk(float a, float b) {
    return __builtin_bit_cast(f16x2, __builtin_amdgcn_cvt_pkrtz(a, b));
}

__device__ __forceinline__ void glds16(const void* g, void* l) {
    __builtin_amdgcn_global_load_lds(
        (const __attribute__((address_space(1))) unsigned int*)g,
        (__attribute__((address_space(3))) unsigned int*)l, 16, 0, 0);
}

// ---------------- router: logits, softmax, top1/top2, gates, + x->fp16 ----------------
__global__ __launch_bounds__(256) void router_kernel(
    const float* __restrict__ x,        // [T, D]
    const float* __restrict__ rw,       // [D, E]
    float* __restrict__ gates_out,      // [T, E]
    float* __restrict__ top1_out,       // [T]
    int*   __restrict__ meta,
    int* __restrict__ e1a, int* __restrict__ e2a,
    float* __restrict__ g1a, float* __restrict__ g2a,
    _Float16* __restrict__ xh)          // [T, D] fp16
{
    const int wid  = threadIdx.x >> 6;
    const int lane = threadIdx.x & 63;
    const int t = blockIdx.x * 4 + wid;

    float acc[NE];
#pragma unroll
    for (int e = 0; e < NE; ++e) acc[e] = 0.f;

#pragma unroll
    for (int i = 0; i < 4; ++i) {
        const int d0 = i * 256 + lane * 4;
        f32x4 xv = *(const f32x4*)&x[(size_t)t * DIM + d0];
        f16x2 h0 = cvtpk(xv[0], xv[1]);
        f16x2 h1 = cvtpk(xv[2], xv[3]);
        f16x4 hv; hv[0] = h0[0]; hv[1] = h0[1]; hv[2] = h1[0]; hv[3] = h1[1];
        *(f16x4*)&xh[(size_t)t * DIM + d0] = hv;
#pragma unroll
        for (int j = 0; j < 4; ++j) {
            f32x4 wa = *(const f32x4*)&rw[(size_t)(d0 + j) * NE];
            f32x4 wb = *(const f32x4*)&rw[(size_t)(d0 + j) * NE + 4];
            float xs = xv[j];
            acc[0] += xs * wa[0]; acc[1] += xs * wa[1];
            acc[2] += xs * wa[2]; acc[3] += xs * wa[3];
            acc[4] += xs * wb[0]; acc[5] += xs * wb[1];
            acc[6] += xs * wb[2]; acc[7] += xs * wb[3];
        }
    }
#pragma unroll
    for (int off = 32; off > 0; off >>= 1) {
#pragma unroll
        for (int e = 0; e < NE; ++e)
            acc[e] += __shfl_xor(acc[e], off, 64);
    }

    float mx = acc[0];
#pragma unroll
    for (int e = 1; e < NE; ++e) mx = fmaxf(mx, acc[e]);
    float pr[NE]; float s = 0.f;
#pragma unroll
    for (int e = 0; e < NE; ++e) { pr[e] = expf(acc[e] - mx); s += pr[e]; }

    int e1 = 0; float b1v = acc[0];
#pragma unroll
    for (int e = 1; e < NE; ++e) if (acc[e] > b1v) { b1v = acc[e]; e1 = e; }
    int e2 = (e1 == 0) ? 1 : 0; float b2v = acc[e2];
#pragma unroll
    for (int e = 0; e < NE; ++e)
        if (e != e1 && acc[e] > b2v) { b2v = acc[e]; e2 = e; }

    float p1 = pr[e1] / s, p2 = pr[e2] / s;
    float denom = fmaxf(p1 + p2, 1.1920929e-07f);
    float gg1 = p1 / denom, gg2 = p2 / denom;

    if (lane == 0) {
#pragma unroll
        for (int e = 0; e < NE; ++e)
            gates_out[(size_t)t * NE + e] = (e == e1) ? gg1 : ((e == e2) ? gg2 : 0.f);
        top1_out[t] = (float)e1;
        e1a[t] = e1; e2a[t] = e2; g1a[t] = gg1; g2a[t] = gg2;
        atomicAdd(&meta[e1], 1);
        atomicAdd(&meta[e2], 1);
    }
}

// ---------------- scan: prefix + tile table ----------------
__global__ void scan_kernel(int* __restrict__ meta, int* __restrict__ tabE, int* __restrict__ tabM) {
    if (threadIdx.x == 0) {
        int s = 0, nt = 0;
#pragma unroll
        for (int e = 0; e < NE; ++e) {
            meta[8 + e] = s;
            int c = meta[e]; s += c;
            for (int m0 = 0; m0 < c; m0 += 128) { tabE[nt] = e; tabM[nt] = m0; ++nt; }
        }
        for (; nt < MAXTILES; ++nt) { tabE[nt] = -1; tabM[nt] = 0; }
    }
}

// ---------------- compaction ----------------
__global__ void compact_kernel(const int* __restrict__ e1a, const int* __restrict__ e2a,
                               int* __restrict__ meta, int* __restrict__ atok,
                               int* __restrict__ tslot)
{
    int t = blockIdx.x * blockDim.x + threadIdx.x;
    if (t >= T_TOK) return;
    int e1 = e1a[t], e2 = e2a[t];
    int s1 = meta[8 + e1] + atomicAdd(&meta[16 + e1], 1);
    atok[s1] = t; tslot[2 * t] = s1;
    int s2 = meta[8 + e2] + atomicAdd(&meta[16 + e2], 1);
    atok[s2] = t; tslot[2 * t + 1] = s2;
}

// B-tile writer fc1: 128 n-rows x 64 k, from 8 f32x4 (8 k-rows x 4 n each)
__device__ __forceinline__ void write_bs1(_Float16* Bs, const f32x4* breg, int bn0, int bk0) {
#pragma unroll
    for (int j = 0; j < 4; ++j) {
        f16x8 hv;
#pragma unroll
        for (int r = 0; r < 4; ++r) {
            f16x2 p = cvtpk(breg[2*r][j], breg[2*r+1][j]);
            hv[2*r] = p[0]; hv[2*r+1] = p[1];
        }
        int row = bn0 + j;
        int kb = (bk0 * 2) ^ ((row & 7) << 4);
        *(f16x8*)((char*)Bs + row * 128 + kb) = hv;
    }
}

// B-tile writer fc2: 64 n-rows x 64 k, from 4 f32x4 (4 k-rows x 4 n each)
__device__ __forceinline__ void write_bs2(_Float16* Bs, const f32x4* breg, int bn0, int bk0) {
#pragma unroll
    for (int j = 0; j < 4; ++j) {
        f16x4 hv;
        f16x2 p0 = cvtpk(breg[0][j], breg[1][j]);
        f16x2 p1 = cvtpk(breg[2][j], breg[3][j]);
        hv[0] = p0[0]; hv[1] = p0[1]; hv[2] = p1[0]; hv[3] = p1[1];
        int row = bn0 + j;
        int kb = (bk0 * 2) ^ ((row & 7) << 4);
        *(f16x4*)((char*)Bs + row * 128 + kb) = hv;
    }
}

// ---------------- fc1: H = relu(Xg @ W1[e] + b1[e]) ----------------
// BM=128 BN=128 BK=64, 4 waves 2x2, A dbuf via global_load_lds, B reg-prefetch
__global__ __launch_bounds__(256, 3) void fc1_kernel(
    const _Float16* __restrict__ xh,    // [T, D] fp16
    const float* __restrict__ w1,       // [E, D, F]
    const float* __restrict__ b1,       // [E, F]
    const int* __restrict__ meta,
    const int* __restrict__ tabE, const int* __restrict__ tabM,
    const int* __restrict__ atok,
    _Float16* __restrict__ H)           // [2T, F]
{
    const int e = tabE[blockIdx.y];
    if (e < 0) return;
    const int m0  = tabM[blockIdx.y];
    const int cnt = meta[e];
    const int base = meta[8 + e];
    const int n0  = blockIdx.x * 128;

    __shared__ __align__(16) _Float16 As[2][128 * 64];
    __shared__ __align__(16) _Float16 Bs[128 * 64];

    const int tid = threadIdx.x, wid = tid >> 6, lane = tid & 63;
    const int wr = wid >> 1, wc = wid & 1;
    const int fr = lane & 15, fq = lane >> 4;

    // A glds per-lane swizzled source addrs (4 instrs/wave, 8 rows each)
    const char* asrc[4];
#pragma unroll
    for (int i = 0; i < 4; ++i) {
        int row = wid * 32 + i * 8 + (lane >> 3);
        int rg = m0 + row; if (rg >= cnt) rg = cnt - 1;
        int tok = atok[base + rg];
        int cb = ((lane & 7) * 16) ^ ((row & 7) << 4);   // swizzled byte within 128B row
        asrc[i] = (const char*)(xh + (size_t)tok * DIM) + cb;
    }

    const int bn0 = (tid & 31) * 4;
    const int bk0 = (tid >> 5) * 8;
    const float* bsrc = w1 + (size_t)e * DIM * FF + n0 + bn0;

    f32x4 acc[4][4];
#pragma unroll
    for (int mi = 0; mi < 4; ++mi)
#pragma unroll
        for (int ni = 0; ni < 4; ++ni) acc[mi][ni] = (f32x4)0.0f;

    f32x4 breg[8];
    const int KS = DIM / 64;

    // prologue: stage tile 0
#pragma unroll
    for (int i = 0; i < 4; ++i)
        glds16(asrc[i], &As[0][(wid * 32 + i * 8) * 64]);
#pragma unroll
    for (int r = 0; r < 8; ++r)
        breg[r] = *(const f32x4*)&bsrc[(size_t)(bk0 + r) * FF];
    asm volatile("s_waitcnt vmcnt(0)" ::: "memory");
    write_bs1(Bs, breg, bn0, bk0);
    asm volatile("s_waitcnt lgkmcnt(0)" ::: "memory");
    __builtin_amdgcn_s_barrier();

    for (int kt = 0; kt < KS; ++kt) {
        const int kn = kt + 1;
        if (kn < KS) {
#pragma unroll
            for (int i = 0; i < 4; ++i)
                glds16(asrc[i] + kn * 128, &As[kn & 1][(wid * 32 + i * 8) * 64]);
#pragma unroll
            for (int r = 0; r < 8; ++r)
                breg[r] = *(const f32x4*)&bsrc[((size_t)kn * 64 + bk0 + r) * FF];
        }
        const _Float16* A = As[kt & 1];
#pragma unroll
        for (int kk = 0; kk < 2; ++kk) {
            f16x8 af[4], bf[4];
#pragma unroll
            for (int mi = 0; mi < 4; ++mi) {
                int row = wr * 64 + mi * 16 + fr;
                int kb = (kk * 64 + fq * 16) ^ ((row & 7) << 4);
                af[mi] = *(const f16x8*)((const char*)(A + row * 64) + kb);
            }
#pragma unroll
            for (int ni = 0; ni < 4; ++ni) {
                int row = wc * 64 + ni * 16 + fr;
                int kb = (kk * 64 + fq * 16) ^ ((row & 7) << 4);
                bf[ni] = *(const f16x8*)((const char*)(Bs + row * 64) + kb);
            }
#pragma unroll
            for (int mi = 0; mi < 4; ++mi)
#pragma unroll
                for (int ni = 0; ni < 4; ++ni)
                    acc[mi][ni] = __builtin_amdgcn_mfma_f32_16x16x32_f16(af[mi], bf[ni], acc[mi][ni], 0, 0, 0);
        }
        asm volatile("s_waitcnt lgkmcnt(0)" ::: "memory");
        __builtin_amdgcn_s_barrier();
        if (kn < KS)
            write_bs1(Bs, breg, bn0, bk0);
        asm volatile("s_waitcnt vmcnt(0) lgkmcnt(0)" ::: "memory");
        __builtin_amdgcn_s_barrier();
    }

    const int crow = wr * 64 + fq * 4;
    const int ccol = wc * 64 + fr;
#pragma unroll
    for (int ni = 0; ni < 4; ++ni) {
        int n = n0 + ccol + ni * 16;
        float bias = b1[(size_t)e * FF + n];
#pragma unroll
        for (int mi = 0; mi < 4; ++mi) {
#pragma unroll
            for (int r = 0; r < 4; ++r) {
                int rg = m0 + crow + mi * 16 + r;
                if (rg < cnt) {
                    float v = fmaxf(acc[mi][ni][r] + bias, 0.f);
                    H[(size_t)(base + rg) * FF + n] = (_Float16)v;
                }
            }
        }
    }
}

// ---------------- fc2: Y = H @ W2[e] + b2[e] ----------------
// BM=128 BN=64 BK=64, 4 waves 2x2 (wave tile 64x32)
__global__ __launch_bounds__(256, 4) void fc2_kernel(
    const _Float16* __restrict__ H,     // [2T, F]
    const float* __restrict__ w2,       // [E, F, D]
    const float* __restrict__ b2,       // [E, D]
    const int* __restrict__ meta,
    const int* __restrict__ tabE, const int* __restrict__ tabM,
    float* __restrict__ Y)              // [2T, D]
{
    const int e = tabE[blockIdx.y];
    if (e < 0) return;
    const int m0  = tabM[blockIdx.y];
    const int cnt = meta[e];
    const int base = meta[8 + e];
    const int n0  = blockIdx.x * 64;

    __shared__ __align__(16) _Float16 As[2][128 * 64];
    __shared__ __align__(16) _Float16 Bs[64 * 64];

    const int tid = threadIdx.x, wid = tid >> 6, lane = tid & 63;
    const int wr = wid >> 1, wc = wid & 1;
    const int fr = lane & 15, fq = lane >> 4;

    const char* asrc[4];
#pragma unroll
    for (int i = 0; i < 4; ++i) {
        int row = wid * 32 + i * 8 + (lane >> 3);
        int rg = m0 + row; if (rg >= cnt) rg = cnt - 1;
        int slot = base + rg;
        int cb = ((lane & 7) * 16) ^ ((row & 7) << 4);
        asrc[i] = (const char*)(H + (size_t)slot * FF) + cb;
    }

    const int bn0 = (tid & 15) * 4;
    const int bk0 = (tid >> 4) * 4;
    const float* bsrc = w2 + (size_t)e * FF * DIM + n0 + bn0;

    f32x4 acc[4][2];
#pragma unroll
    for (int mi = 0; mi < 4; ++mi)
#pragma unroll
        for (int ni = 0; ni < 2; ++ni) acc[mi][ni] = (f32x4)0.0f;

    f32x4 breg[4];
    const int KS = FF / 64;

#pragma unroll
    for (int i = 0; i < 4; ++i)
        glds16(asrc[i], &As[0][(wid * 32 + i * 8) * 64]);
#pragma unroll
    for (int r = 0; r < 4; ++r)
        breg[r] = *(const f32x4*)&bsrc[(size_t)(bk0 + r) * DIM];
    asm volatile("s_waitcnt vmcnt(0)" ::: "memory");
    write_bs2(Bs, breg, bn0, bk0);
    asm volatile("s_waitcnt lgkmcnt(0)" ::: "memory");
    __builtin_amdgcn_s_barrier();

    for (int kt = 0; kt < KS; ++kt) {
        const int kn = kt + 1;
        if (kn < KS) {
#pragma unroll
            for (int i = 0; i < 4; ++i)
                glds16(asrc[i] + kn * 128, &As[kn & 1][(wid * 32 + i * 8) * 64]);
#pragma unroll
            for (int r = 0; r < 4; ++r)
                breg[r] = *(const f32x4*)&bsrc[((size_t)kn * 64 + bk0 + r) * DIM];
        }
        const _Float16* A = As[kt & 1];
#pragma unroll
        for (int kk = 0; kk < 2; ++kk) {
            f16x8 af[4], bf[2];
#pragma unroll
            for (int mi = 0; mi < 4; ++mi) {
                int row = wr * 64 + mi * 16 + fr;
                int kb = (kk * 64 + fq * 16) ^ ((row & 7) << 4);
                af[mi] = *(const f16x8*)((const char*)(A + row * 64) + kb);
            }
#pragma unroll
            for (int ni = 0; ni < 2; ++ni) {
                int row = wc * 32 + ni * 16 + fr;
                int kb = (kk * 64 + fq * 16) ^ ((row & 7) << 4);
                bf[ni] = *(const f16x8*)((const char*)(Bs + row * 64) + kb);
            }
#pragma unroll
            for (int mi = 0; mi < 4; ++mi)
#pragma unroll
                for (int ni = 0; ni < 2; ++ni)
                    acc[mi][ni] = __builtin_amdgcn_mfma_f32_16x16x32_f16(af[mi], bf[ni], acc[mi][ni], 0, 0, 0);
        }
        asm volatile("s_waitcnt lgkmcnt(0)" ::: "memory");
        __builtin_amdgcn_s_barrier();
        if (kn < KS)
            write_bs2(Bs, breg, bn0, bk0);
        asm volatile("s_waitcnt vmcnt(0) lgkmcnt(0)" ::: "memory");
        __builtin_amdgcn_s_barrier();
    }

    const int crow = wr * 64 + fq * 4;
    const int ccol = wc * 32 + fr;
#pragma unroll
    for (int ni = 0; ni < 2; ++ni) {
        int n = n0 + ccol + ni * 16;
        float bias = b2[(size_t)e * DIM + n];
#pragma unroll
        for (int mi = 0; mi < 4; ++mi) {
#pragma unroll
            for (int r = 0; r < 4; ++r) {
                int rg = m0 + crow + mi * 16 + r;
                if (rg < cnt)
                    Y[(size_t)(base + rg) * DIM + n] = acc[mi][ni][r] + bias;
            }
        }
    }
}

// ---------------- combine ----------------
__global__ __launch_bounds__(256) void combine_kernel(
    const float* __restrict__ x, const float* __restrict__ Y,
    const int* __restrict__ tslot, const float* __restrict__ g1a,
    const float* __restrict__ g2a, float* __restrict__ out)
{
    const int t = blockIdx.x;
    const int d = threadIdx.x * 4;
    const int s1 = tslot[2 * t], s2 = tslot[2 * t + 1];
    const float a = g1a[t], b = g2a[t];
    f32x4 y1 = *(const f32x4*)&Y[(size_t)s1 * DIM + d];
    f32x4 y2 = *(const f32x4*)&Y[(size_t)s2 * DIM + d];
    f32x4 xv = *(const f32x4*)&x[(size_t)t * DIM + d];
    f32x4 o;
#pragma unroll
    for (int j = 0; j < 4; ++j) {
        float v = a * y1[j] + b * y2[j];
        o[j] = (v == 0.f) ? xv[j] : v;
    }
    *(f32x4*)&out[(size_t)t * DIM + d] = o;
}

extern "C" void kernel_launch(void* const* d_in, const int* in_sizes, int n_in,
                              void* d_out, int out_size, void* d_ws, size_t ws_size,
                              hipStream_t stream) {
    (void)in_sizes; (void)n_in; (void)out_size; (void)ws_size;
    const float* x  = (const float*)d_in[0];
    const float* rw = (const float*)d_in[1];
    const float* w1 = (const float*)d_in[2];
    const float* b1 = (const float*)d_in[3];
    const float* w2 = (const float*)d_in[4];
    const float* b2 = (const float*)d_in[5];

    float* out       = (float*)d_out;
    float* gates_out = out + (size_t)T_TOK * DIM;
    float* top1_out  = gates_out + (size_t)T_TOK * NE;

    char* ws = (char*)d_ws;
    int*   meta  = (int*)ws;                       // [0..7] counts, [8..15] base, [16..23] cursor
    int*   tabE  = (int*)(ws + 256);
    int*   tabM  = (int*)(ws + 512);
    int*   e1a   = (int*)(ws + 1024);
    int*   e2a   = (int*)(ws + 1024 + 8192);
    float* g1a   = (float*)(ws + 1024 + 2 * 8192);
    float* g2a   = (float*)(ws + 1024 + 3 * 8192);
    int*   atok  = (int*)(ws + 1024 + 4 * 8192);             // [2T]
    int*   tslot = (int*)(ws + 1024 + 4 * 8192 + 16384);     // [2T]
    _Float16* H  = (_Float16*)(ws + 66560);                  // [2T, F] fp16 = 16 MB
    _Float16* xh = (_Float16*)(ws + 66560 + (size_t)16 * 1024 * 1024);  // [T, D] fp16 = 4 MB
    float*    Y  = (float*)(ws + 66560 + (size_t)16 * 1024 * 1024);     // [2T, D] f32 (aliases xh: xh dead after fc1)

    (void)hipMemsetAsync(meta, 0, 256, stream);
    router_kernel<<<T_TOK / 4, 256, 0, stream>>>(x, rw, gates_out, top1_out, meta, e1a, e2a, g1a, g2a, xh);
    scan_kernel<<<1, 64, 0, stream>>>(meta, tabE, tabM);
    compact_kernel<<<T_TOK / 256, 256, 0, stream>>>(e1a, e2a, meta, atok, tslot);
    fc1_kernel<<<dim3(FF / 128, MAXTILES), 256, 0, stream>>>(xh, w1, b1, meta, tabE, tabM, atok, H);
    fc2_kernel<<<dim3(DIM / 64, MAXTILES), 256, 0, stream>>>(H, w2, b2, meta, tabE, tabM, Y);
    combine_kernel<<<T_TOK, 256, 0, stream>>>(x, Y, tslot, g1a, g2a, out);
}